// Round 1
// baseline (1188.395 us; speedup 1.0000x reference)
//
#include <hip/hip_runtime.h>

#define NNODES 12288
#define ETOT   73728
#define NGR    1024

typedef __attribute__((ext_vector_type(8))) short short8;
typedef __attribute__((ext_vector_type(4))) float f32x4;

__device__ __forceinline__ unsigned short f2b(float f) {
  unsigned x = __float_as_uint(f);
  return (unsigned short)((x + 0x7FFFu + ((x >> 16) & 1u)) >> 16);
}
__device__ __forceinline__ float b2f(unsigned short u) {
  return __uint_as_float(((unsigned)u) << 16);
}
__device__ __forceinline__ void load_lds16(const void* g, void* l) {
  __builtin_amdgcn_global_load_lds(
      (const __attribute__((address_space(1))) unsigned int*)g,
      (__attribute__((address_space(3))) unsigned int*)l, 16, 0, 0);
}

// ---------------------------------------------------------------------------
// Pack: transpose-convert all weights to bf16 [N][K] (row = out col), build
// per-layer concatenated projection weights + biases, convert x to bf16.
// wt_my layout (rows n' of 3072): [0,1024) gat_Wl[l,0] | [1024,2048) gat_Wr[l,1]
//  | [2048,2304) cg_Wf[l,0] bottom | [2304,2560) cg_Ws[l,0] bottom
//  | [2560,2816) cg_Wf[l,1] top    | [2816,3072) cg_Ws[l,1] top
// wt_opp: gat_Wr[l,0] | gat_Wl[l,1] | cg_Wf[l,0] top | cg_Ws[l,0] top
//  | cg_Wf[l,1] bottom | cg_Ws[l,1] bottom
// ---------------------------------------------------------------------------
__global__ void pack_kernel(
    const float* __restrict__ gat_Wl, const float* __restrict__ gat_Wr,
    const float* __restrict__ cg_Wf, const float* __restrict__ cg_Ws,
    const float* __restrict__ node_W, const float* __restrict__ enc_W,
    const float* __restrict__ fin_W1,
    const float* __restrict__ gat_bl, const float* __restrict__ gat_br,
    const float* __restrict__ cg_bf, const float* __restrict__ cg_bs,
    const float* __restrict__ x_my, const float* __restrict__ x_opp,
    unsigned short* __restrict__ wt_my, unsigned short* __restrict__ wt_opp,
    unsigned short* __restrict__ node_wt, unsigned short* __restrict__ enc_wt,
    unsigned short* __restrict__ fin_w1t,
    float* __restrict__ bias_my, float* __restrict__ bias_opp,
    unsigned short* __restrict__ xb)
{
  int idx = blockIdx.x * 256 + threadIdx.x;
  if (idx < 2 * 2359296) {
    int which = idx >= 2359296;
    int t = which ? idx - 2359296 : idx;
    int l = t / 786432;
    int r = t - l * 786432;
    int n = r >> 8, k = r & 255;
    float v;
    if (!which) {
      if (n < 1024)      v = gat_Wl[((l*2+0)*256 + k)*1024 + n];
      else if (n < 2048) v = gat_Wr[((l*2+1)*256 + k)*1024 + (n-1024)];
      else if (n < 2304) v = cg_Wf[((l*2+0)*512 + 256 + k)*256 + (n-2048)];
      else if (n < 2560) v = cg_Ws[((l*2+0)*512 + 256 + k)*256 + (n-2304)];
      else if (n < 2816) v = cg_Wf[((l*2+1)*512 + k)*256 + (n-2560)];
      else               v = cg_Ws[((l*2+1)*512 + k)*256 + (n-2816)];
      wt_my[t] = f2b(v);
    } else {
      if (n < 1024)      v = gat_Wr[((l*2+0)*256 + k)*1024 + n];
      else if (n < 2048) v = gat_Wl[((l*2+1)*256 + k)*1024 + (n-1024)];
      else if (n < 2304) v = cg_Wf[((l*2+0)*512 + k)*256 + (n-2048)];
      else if (n < 2560) v = cg_Ws[((l*2+0)*512 + k)*256 + (n-2304)];
      else if (n < 2816) v = cg_Wf[((l*2+1)*512 + 256 + k)*256 + (n-2560)];
      else               v = cg_Ws[((l*2+1)*512 + 256 + k)*256 + (n-2816)];
      wt_opp[t] = f2b(v);
    }
    return;
  }
  idx -= 2 * 2359296;
  if (idx < 196608) {                       // node_W transpose
    int l = idx / 65536, r = idx - l * 65536;
    int n = r >> 8, k = r & 255;
    node_wt[idx] = f2b(node_W[(l*256 + k)*256 + n]);
    return;
  }
  idx -= 196608;
  if (idx < 8192) {                         // enc_W transpose [256][32]
    int n = idx >> 5, k = idx & 31;
    enc_wt[idx] = f2b(enc_W[k*256 + n]);
    return;
  }
  idx -= 8192;
  if (idx < 32768) {                        // fin_W1 transpose [128][256]
    int n = idx >> 8, k = idx & 255;
    fin_w1t[idx] = f2b(fin_W1[k*128 + n]);
    return;
  }
  idx -= 32768;
  if (idx < 9216) {                         // bias_my
    int l = idx / 3072, n = idx - l * 3072;
    float v;
    if (n < 1024)      v = gat_bl[(l*2+0)*1024 + n];
    else if (n < 2048) v = gat_br[(l*2+1)*1024 + (n-1024)];
    else if (n < 2560) v = 0.f;
    else if (n < 2816) v = cg_bf[(l*2+1)*256 + (n-2560)];
    else               v = cg_bs[(l*2+1)*256 + (n-2816)];
    bias_my[idx] = v;
    return;
  }
  idx -= 9216;
  if (idx < 9216) {                         // bias_opp
    int l = idx / 3072, n = idx - l * 3072;
    float v;
    if (n < 1024)      v = gat_br[(l*2+0)*1024 + n];
    else if (n < 2048) v = gat_bl[(l*2+1)*1024 + (n-1024)];
    else if (n < 2304) v = cg_bf[(l*2+0)*256 + (n-2048)];
    else if (n < 2560) v = cg_bs[(l*2+0)*256 + (n-2304)];
    else               v = 0.f;
    bias_opp[idx] = v;
    return;
  }
  idx -= 9216;
  if (idx < 2 * 393216) {                   // x -> bf16
    xb[idx] = f2b(idx < 393216 ? x_my[idx] : x_opp[idx - 393216]);
  }
}

// ---------------------------------------------------------------------------
// bf16 GEMM, 128x128 tile, BK=32, 4 waves, 16x16x32 MFMA, global_load_lds.
// A [M][lda] bf16 row-major, Wt [Ntot][K] bf16 (pre-transposed weight),
// C [M][ldc] bf16 = A@W + bias (act=1: leaky_relu slope 128).
// ---------------------------------------------------------------------------
__global__ __launch_bounds__(256) void gemm128(
    const unsigned short* __restrict__ A, int lda,
    const unsigned short* __restrict__ Wt,
    const float* __restrict__ bias,
    unsigned short* __restrict__ C, int ldc,
    int K, int act)
{
  __shared__ __align__(16) unsigned short lA[128 * 32];
  __shared__ __align__(16) unsigned short lB[128 * 32];
  const int tid = threadIdx.x;
  const int lane = tid & 63;
  const int w = tid >> 6;
  const int wr = w >> 1, wc = w & 1;
  const int tileM = blockIdx.x * 128;
  const int tileN = blockIdx.y * 128;
  const int r0 = lane & 15;
  const int kb = (lane >> 4) * 8;

  f32x4 acc[4][4];
#pragma unroll
  for (int m = 0; m < 4; ++m)
#pragma unroll
    for (int n = 0; n < 4; ++n)
      acc[m][n] = (f32x4){0.f, 0.f, 0.f, 0.f};

  const int KT = K >> 5;
  for (int kt = 0; kt < KT; ++kt) {
    const int k0 = kt * 32;
#pragma unroll
    for (int p = 0; p < 2; ++p) {
      int idx = p * 256 + tid;
      int rr = idx >> 2, seg = idx & 3;
      load_lds16(A + (size_t)(tileM + rr) * lda + k0 + seg * 8, &lA[idx * 8]);
      load_lds16(Wt + (size_t)(tileN + rr) * K + k0 + seg * 8, &lB[idx * 8]);
    }
    __syncthreads();
    short8 af[4], bfr[4];
#pragma unroll
    for (int m = 0; m < 4; ++m)
      af[m] = *(const short8*)&lA[(wr * 64 + m * 16 + r0) * 32 + kb];
#pragma unroll
    for (int n = 0; n < 4; ++n)
      bfr[n] = *(const short8*)&lB[(wc * 64 + n * 16 + r0) * 32 + kb];
#pragma unroll
    for (int m = 0; m < 4; ++m)
#pragma unroll
      for (int n = 0; n < 4; ++n)
        acc[m][n] = __builtin_amdgcn_mfma_f32_16x16x32_bf16(af[m], bfr[n], acc[m][n], 0, 0, 0);
    __syncthreads();
  }
#pragma unroll
  for (int m = 0; m < 4; ++m) {
#pragma unroll
    for (int n = 0; n < 4; ++n) {
      const int col = tileN + wc * 64 + n * 16 + r0;
      const float bv = bias[col];
#pragma unroll
      for (int r = 0; r < 4; ++r) {
        const int row = tileM + wr * 64 + m * 16 + (lane >> 4) * 4 + r;
        float v = acc[m][n][r] + bv;
        if (act) v = v > 0.f ? v : 128.f * v;
        C[(size_t)row * ldc + col] = f2b(v);
      }
    }
  }
}

// ---------------------------------------------------------------------------
// GATv2 edge stage: one block per graph. projS/projD point at the 1024-col
// slice (stride 3072). Softmax per (dst,head), A-matrix aggregation.
// ---------------------------------------------------------------------------
__global__ __launch_bounds__(256) void gat_edge(
    const unsigned short* __restrict__ projS,
    const unsigned short* __restrict__ projD,
    const int* __restrict__ edges,
    const float* __restrict__ att,
    const float* __restrict__ gbias,
    float* __restrict__ outp)
{
  __shared__ __align__(8) unsigned short xl[12 * 4 * 260];
  __shared__ __align__(8) unsigned short xr[12 * 4 * 260];
  __shared__ float attS[4 * 260];
  __shared__ float alpha[72 * 4];
  __shared__ float Amat[12 * 12 * 4];
  __shared__ float dden[48];
  __shared__ int se[72], de[72];
  const int g = blockIdx.x, tid = threadIdx.x;
  const int base = g * 12;
  if (tid < 72) {
    se[tid] = edges[g * 72 + tid] - base;
    de[tid] = edges[ETOT + g * 72 + tid] - base;
  }
  for (int i = tid; i < 1024; i += 256)
    attS[(i >> 8) * 260 + (i & 255)] = att[i];
  for (int i = tid; i < 12 * 256; i += 256) {
    int s = i >> 8, c4 = (i & 255) * 4;
    int h = c4 >> 8, cc = c4 & 255;
    ushort4 v1 = *(const ushort4*)(projS + (size_t)(base + s) * 3072 + c4);
    ushort4 v2 = *(const ushort4*)(projD + (size_t)(base + s) * 3072 + c4);
    *(ushort4*)&xl[(s * 4 + h) * 260 + cc] = v1;
    *(ushort4*)&xr[(s * 4 + h) * 260 + cc] = v2;
  }
  __syncthreads();
  for (int t = tid; t < 288; t += 256) {
    const int e = t >> 2, h = t & 3;
    const unsigned short* pl = &xl[(se[e] * 4 + h) * 260];
    const unsigned short* pr = &xr[(de[e] * 4 + h) * 260];
    const float* pa = &attS[h * 260];
    float sum = 0.f;
    for (int c = 0; c < 256; ++c) {
      float v = b2f(pl[c]) + b2f(pr[c]);
      v = v > 0.f ? v : 0.2f * v;
      sum += v * pa[c];
    }
    alpha[e * 4 + h] = sum;
  }
  __syncthreads();
  if (tid < 48) {
    const int d = tid >> 2, h = tid & 3;
    float mx = -1e30f;
    for (int e = 0; e < 72; ++e)
      if (de[e] == d) mx = fmaxf(mx, alpha[e * 4 + h]);
#pragma unroll
    for (int s = 0; s < 12; ++s) Amat[(d * 12 + s) * 4 + h] = 0.f;
    float dn = 0.f;
    for (int e = 0; e < 72; ++e)
      if (de[e] == d) {
        float wv = __expf(alpha[e * 4 + h] - mx);
        dn += wv;
        Amat[(d * 12 + se[e]) * 4 + h] += wv;
      }
    dden[tid] = dn;
  }
  __syncthreads();
  for (int t = tid; t < 12 * 256; t += 256) {
    const int d = t >> 8, cc = t & 255;
    float o = 0.f;
#pragma unroll
    for (int h = 0; h < 4; ++h) {
      float a0 = 0.f;
#pragma unroll
      for (int s = 0; s < 12; ++s)
        a0 += Amat[(d * 12 + s) * 4 + h] * b2f(xl[(s * 4 + h) * 260 + cc]);
      o += a0 / (dden[d * 4 + h] + 1e-16f);
    }
    outp[(size_t)(base + d) * 256 + cc] = 0.25f * o + gbias[cc];
  }
}

// ---------------------------------------------------------------------------
// CGConv edge stage + combine: out = bf16( h_dst + gat_dst + sum_msg ).
// pdF/pdS/psF/psS point at 256-col slices (stride 3072).
// ---------------------------------------------------------------------------
__global__ __launch_bounds__(256) void cg_edge(
    const unsigned short* __restrict__ pdF, const unsigned short* __restrict__ pdS,
    const unsigned short* __restrict__ psF, const unsigned short* __restrict__ psS,
    const unsigned short* __restrict__ hres,
    const float* __restrict__ gatp,
    const int* __restrict__ edges,
    unsigned short* __restrict__ outp)
{
  __shared__ __align__(8) unsigned short df[12 * 256], dsb[12 * 256];
  __shared__ __align__(8) unsigned short sfb[12 * 256], ssb[12 * 256];
  __shared__ float outb[12 * 256];
  __shared__ int se[72], de[72];
  const int g = blockIdx.x, tid = threadIdx.x;
  const int base = g * 12;
  if (tid < 72) {
    se[tid] = edges[g * 72 + tid] - base;
    de[tid] = edges[ETOT + g * 72 + tid] - base;
  }
  for (int i = tid; i < 768; i += 256) {
    int s = i >> 6, c4 = (i & 63) * 4;
    size_t gb = (size_t)(base + s) * 3072 + c4;
    *(ushort4*)&df[s * 256 + c4]  = *(const ushort4*)(pdF + gb);
    *(ushort4*)&dsb[s * 256 + c4] = *(const ushort4*)(pdS + gb);
    *(ushort4*)&sfb[s * 256 + c4] = *(const ushort4*)(psF + gb);
    *(ushort4*)&ssb[s * 256 + c4] = *(const ushort4*)(psS + gb);
  }
  for (int i = tid; i < 12 * 256; i += 256) {
    int d = i >> 8, c = i & 255;
    outb[i] = b2f(hres[(size_t)(base + d) * 256 + c]) + gatp[(size_t)(base + d) * 256 + c];
  }
  __syncthreads();
  const int c = tid;
  for (int e = 0; e < 72; ++e) {
    const int s = se[e], d = de[e];
    float zf = b2f(df[d * 256 + c]) + b2f(sfb[s * 256 + c]);
    float zs = b2f(dsb[d * 256 + c]) + b2f(ssb[s * 256 + c]);
    float gate = 1.f / (1.f + __expf(-zf));
    float sp = fmaxf(zs, 0.f) + log1pf(__expf(-fabsf(zs)));
    outb[d * 256 + c] += gate * sp;
  }
  for (int i = tid; i < 12 * 256; i += 256)
    outp[(size_t)(base + (i >> 8)) * 256 + (i & 255)] = f2b(outb[i]);
}

// ---------------------------------------------------------------------------
// logits: one wave per node, dot(f[128], W2) + b2
// ---------------------------------------------------------------------------
__global__ __launch_bounds__(256) void logits_kernel(
    const unsigned short* __restrict__ f, const float* __restrict__ W2,
    const float* __restrict__ b2, float* __restrict__ out)
{
  const int node = blockIdx.x * 4 + (threadIdx.x >> 6);
  const int lane = threadIdx.x & 63;
  const size_t o = (size_t)node * 128 + lane * 2;
  float s = b2f(f[o]) * W2[lane * 2] + b2f(f[o + 1]) * W2[lane * 2 + 1];
  for (int d = 32; d > 0; d >>= 1) s += __shfl_down(s, d, 64);
  if (lane == 0) out[node] = s + b2[0];
}

// ---------------------------------------------------------------------------
extern "C" void kernel_launch(void* const* d_in, const int* in_sizes, int n_in,
                              void* d_out, int out_size, void* d_ws, size_t ws_size,
                              hipStream_t stream) {
  const float* x_my    = (const float*)d_in[0];
  const float* x_opp   = (const float*)d_in[1];
  const int*   e_beats = (const int*)d_in[2];
  const int*   e_loses = (const int*)d_in[3];
  const int*   e_rb    = (const int*)d_in[4];
  const int*   e_rl    = (const int*)d_in[5];
  const float* enc_W   = (const float*)d_in[7];
  const float* enc_b   = (const float*)d_in[8];
  const float* gat_Wl  = (const float*)d_in[9];
  const float* gat_bl  = (const float*)d_in[10];
  const float* gat_Wr  = (const float*)d_in[11];
  const float* gat_br  = (const float*)d_in[12];
  const float* gat_att = (const float*)d_in[13];
  const float* gat_bsp = (const float*)d_in[14];
  const float* cg_Wf   = (const float*)d_in[15];
  const float* cg_bf   = (const float*)d_in[16];
  const float* cg_Ws   = (const float*)d_in[17];
  const float* cg_bs   = (const float*)d_in[18];
  const float* node_W  = (const float*)d_in[19];
  const float* node_b  = (const float*)d_in[20];
  const float* fin_W1  = (const float*)d_in[21];
  const float* fin_b1  = (const float*)d_in[22];
  const float* fin_W2  = (const float*)d_in[23];
  const float* fin_b2  = (const float*)d_in[24];

  char* wsp = (char*)d_ws;
  size_t off = 0;
  auto alloc = [&](size_t b) { char* p = wsp + off; off += (b + 255) & ~(size_t)255; return p; };
  unsigned short* wt_my   = (unsigned short*)alloc((size_t)2359296 * 2);
  unsigned short* wt_opp  = (unsigned short*)alloc((size_t)2359296 * 2);
  unsigned short* node_wt = (unsigned short*)alloc((size_t)196608 * 2);
  unsigned short* enc_wt  = (unsigned short*)alloc((size_t)8192 * 2);
  unsigned short* fin_w1t = (unsigned short*)alloc((size_t)32768 * 2);
  float*          bias_my = (float*)alloc((size_t)9216 * 4);
  float*          bias_op = (float*)alloc((size_t)9216 * 4);
  unsigned short* xb      = (unsigned short*)alloc((size_t)786432 * 2);
  unsigned short* Hb      = (unsigned short*)alloc((size_t)2 * NNODES * 256 * 2);
  unsigned short* proj_my = (unsigned short*)alloc((size_t)NNODES * 3072 * 2);
  unsigned short* proj_op = (unsigned short*)alloc((size_t)NNODES * 3072 * 2);
  float*          gat_my  = (float*)alloc((size_t)NNODES * 256 * 4);
  float*          gat_op  = (float*)alloc((size_t)NNODES * 256 * 4);
  unsigned short* node_in = (unsigned short*)alloc((size_t)2 * NNODES * 256 * 2);
  unsigned short* fbuf    = (unsigned short*)alloc((size_t)NNODES * 128 * 2);

  const int PACK_TOTAL = 2 * 2359296 + 196608 + 8192 + 32768 + 2 * 9216 + 2 * 393216;
  pack_kernel<<<(PACK_TOTAL + 255) / 256, 256, 0, stream>>>(
      gat_Wl, gat_Wr, cg_Wf, cg_Ws, node_W, enc_W, fin_W1,
      gat_bl, gat_br, cg_bf, cg_bs, x_my, x_opp,
      wt_my, wt_opp, node_wt, enc_wt, fin_w1t, bias_my, bias_op, xb);

  // encoder: h(my|opp) = x @ enc_W + enc_b   (M = 2N, K = 32)
  gemm128<<<dim3(192, 2), 256, 0, stream>>>(xb, 32, enc_wt, enc_b, Hb, 256, 32, 0);

  unsigned short* Hmy   = Hb;
  unsigned short* Hopp  = Hb + (size_t)NNODES * 256;
  unsigned short* ni_my = node_in;
  unsigned short* ni_op = node_in + (size_t)NNODES * 256;

  for (int l = 0; l < 3; ++l) {
    gemm128<<<dim3(96, 24), 256, 0, stream>>>(Hmy, 256, wt_my + (size_t)l * 786432,
                                              bias_my + l * 3072, proj_my, 3072, 256, 0);
    gemm128<<<dim3(96, 24), 256, 0, stream>>>(Hopp, 256, wt_opp + (size_t)l * 786432,
                                              bias_op + l * 3072, proj_op, 3072, 256, 0);
    // GAT beats: src=my, dst=opp
    gat_edge<<<NGR, 256, 0, stream>>>(proj_my, proj_op, e_beats,
                                      gat_att + (l * 2 + 0) * 1024,
                                      gat_bsp + (l * 2 + 0) * 256, gat_op);
    // GAT rev_loses: src=opp, dst=my
    gat_edge<<<NGR, 256, 0, stream>>>(proj_op + 1024, proj_my + 1024, e_rl,
                                      gat_att + (l * 2 + 1) * 1024,
                                      gat_bsp + (l * 2 + 1) * 256, gat_my);
    // CG loses: src=my, dst=opp
    cg_edge<<<NGR, 256, 0, stream>>>(proj_op + 2048, proj_op + 2304,
                                     proj_my + 2048, proj_my + 2304,
                                     Hopp, gat_op, e_loses, ni_op);
    // CG rev_beats: src=opp, dst=my
    cg_edge<<<NGR, 256, 0, stream>>>(proj_my + 2560, proj_my + 2816,
                                     proj_op + 2560, proj_op + 2816,
                                     Hmy, gat_my, e_rb, ni_my);
    // node linear (both types, same weight)
    gemm128<<<dim3(192, 2), 256, 0, stream>>>(node_in, 256, node_wt + (size_t)l * 65536,
                                              node_b + l * 256, Hb, 256, 256, 0);
  }

  // final encoder: f = leaky_relu(h_my @ W1 + b1, 128)
  gemm128<<<dim3(96, 1), 256, 0, stream>>>(Hmy, 256, fin_w1t, fin_b1, fbuf, 128, 256, 1);
  logits_kernel<<<NNODES / 4, 256, 0, stream>>>(fbuf, fin_W2, fin_b2, (float*)d_out);
}

// Round 2
// 834.281 us; speedup vs baseline: 1.4245x; 1.4245x over previous
//
#include <hip/hip_runtime.h>

#define NNODES 12288
#define ETOT   73728
#define NGR    1024
#define LOG2E  1.442695041f
#define LN2    0.6931471806f

typedef __attribute__((ext_vector_type(8))) short short8;
typedef __attribute__((ext_vector_type(4))) float f32x4;

__device__ __forceinline__ unsigned short f2b(float f) {
  unsigned x = __float_as_uint(f);
  return (unsigned short)((x + 0x7FFFu + ((x >> 16) & 1u)) >> 16);
}
__device__ __forceinline__ float b2f(unsigned short u) {
  return __uint_as_float(((unsigned)u) << 16);
}
__device__ __forceinline__ void load_lds16(const void* g, void* l) {
  __builtin_amdgcn_global_load_lds(
      (const __attribute__((address_space(1))) unsigned int*)g,
      (__attribute__((address_space(3))) unsigned int*)l, 16, 0, 0);
}

// ---------------------------------------------------------------------------
// Pack (unchanged from R0): transpose-convert all weights to bf16 [N][K].
// ---------------------------------------------------------------------------
__global__ void pack_kernel(
    const float* __restrict__ gat_Wl, const float* __restrict__ gat_Wr,
    const float* __restrict__ cg_Wf, const float* __restrict__ cg_Ws,
    const float* __restrict__ node_W, const float* __restrict__ enc_W,
    const float* __restrict__ fin_W1,
    const float* __restrict__ gat_bl, const float* __restrict__ gat_br,
    const float* __restrict__ cg_bf, const float* __restrict__ cg_bs,
    const float* __restrict__ x_my, const float* __restrict__ x_opp,
    unsigned short* __restrict__ wt_my, unsigned short* __restrict__ wt_opp,
    unsigned short* __restrict__ node_wt, unsigned short* __restrict__ enc_wt,
    unsigned short* __restrict__ fin_w1t,
    float* __restrict__ bias_my, float* __restrict__ bias_opp,
    unsigned short* __restrict__ xb)
{
  int idx = blockIdx.x * 256 + threadIdx.x;
  if (idx < 2 * 2359296) {
    int which = idx >= 2359296;
    int t = which ? idx - 2359296 : idx;
    int l = t / 786432;
    int r = t - l * 786432;
    int n = r >> 8, k = r & 255;
    float v;
    if (!which) {
      if (n < 1024)      v = gat_Wl[((l*2+0)*256 + k)*1024 + n];
      else if (n < 2048) v = gat_Wr[((l*2+1)*256 + k)*1024 + (n-1024)];
      else if (n < 2304) v = cg_Wf[((l*2+0)*512 + 256 + k)*256 + (n-2048)];
      else if (n < 2560) v = cg_Ws[((l*2+0)*512 + 256 + k)*256 + (n-2304)];
      else if (n < 2816) v = cg_Wf[((l*2+1)*512 + k)*256 + (n-2560)];
      else               v = cg_Ws[((l*2+1)*512 + k)*256 + (n-2816)];
      wt_my[t] = f2b(v);
    } else {
      if (n < 1024)      v = gat_Wr[((l*2+0)*256 + k)*1024 + n];
      else if (n < 2048) v = gat_Wl[((l*2+1)*256 + k)*1024 + (n-1024)];
      else if (n < 2304) v = cg_Wf[((l*2+0)*512 + k)*256 + (n-2048)];
      else if (n < 2560) v = cg_Ws[((l*2+0)*512 + k)*256 + (n-2304)];
      else if (n < 2816) v = cg_Wf[((l*2+1)*512 + 256 + k)*256 + (n-2560)];
      else               v = cg_Ws[((l*2+1)*512 + 256 + k)*256 + (n-2816)];
      wt_opp[t] = f2b(v);
    }
    return;
  }
  idx -= 2 * 2359296;
  if (idx < 196608) {
    int l = idx / 65536, r = idx - l * 65536;
    int n = r >> 8, k = r & 255;
    node_wt[idx] = f2b(node_W[(l*256 + k)*256 + n]);
    return;
  }
  idx -= 196608;
  if (idx < 8192) {
    int n = idx >> 5, k = idx & 31;
    enc_wt[idx] = f2b(enc_W[k*256 + n]);
    return;
  }
  idx -= 8192;
  if (idx < 32768) {
    int n = idx >> 8, k = idx & 255;
    fin_w1t[idx] = f2b(fin_W1[k*128 + n]);
    return;
  }
  idx -= 32768;
  if (idx < 9216) {
    int l = idx / 3072, n = idx - l * 3072;
    float v;
    if (n < 1024)      v = gat_bl[(l*2+0)*1024 + n];
    else if (n < 2048) v = gat_br[(l*2+1)*1024 + (n-1024)];
    else if (n < 2560) v = 0.f;
    else if (n < 2816) v = cg_bf[(l*2+1)*256 + (n-2560)];
    else               v = cg_bs[(l*2+1)*256 + (n-2816)];
    bias_my[idx] = v;
    return;
  }
  idx -= 9216;
  if (idx < 9216) {
    int l = idx / 3072, n = idx - l * 3072;
    float v;
    if (n < 1024)      v = gat_br[(l*2+0)*1024 + n];
    else if (n < 2048) v = gat_bl[(l*2+1)*1024 + (n-1024)];
    else if (n < 2304) v = cg_bf[(l*2+0)*256 + (n-2048)];
    else if (n < 2560) v = cg_bs[(l*2+0)*256 + (n-2304)];
    else               v = 0.f;
    bias_opp[idx] = v;
    return;
  }
  idx -= 9216;
  if (idx < 2 * 393216) {
    xb[idx] = f2b(idx < 393216 ? x_my[idx] : x_opp[idx - 393216]);
  }
}

// ---------------------------------------------------------------------------
// bf16 GEMM, 128x128 tile, BK=32, 4 waves, 16x16x32 MFMA, global_load_lds.
// T2-style seg-XOR swizzle: seg' = seg ^ ((row>>1)&3), applied to the GLOBAL
// source address (linear LDS dest, rule 21) and to the ds_read_b128 address.
// ---------------------------------------------------------------------------
__global__ __launch_bounds__(256) void gemm128(
    const unsigned short* __restrict__ A, int lda,
    const unsigned short* __restrict__ Wt,
    const float* __restrict__ bias,
    unsigned short* __restrict__ C, int ldc,
    int K, int act)
{
  __shared__ __align__(16) unsigned short lA[128 * 32];
  __shared__ __align__(16) unsigned short lB[128 * 32];
  const int tid = threadIdx.x;
  const int lane = tid & 63;
  const int w = tid >> 6;
  const int wr = w >> 1, wc = w & 1;
  const int tileM = blockIdx.x * 128;
  const int tileN = blockIdx.y * 128;
  const int r0 = lane & 15;
  const int kq = lane >> 4;
  const int segr = (kq ^ ((r0 >> 1) & 3)) * 8;   // swizzled read k-offset

  f32x4 acc[4][4];
#pragma unroll
  for (int m = 0; m < 4; ++m)
#pragma unroll
    for (int n = 0; n < 4; ++n)
      acc[m][n] = (f32x4){0.f, 0.f, 0.f, 0.f};

  const int KT = K >> 5;
  for (int kt = 0; kt < KT; ++kt) {
    const int k0 = kt * 32;
#pragma unroll
    for (int p = 0; p < 2; ++p) {
      int idx = p * 256 + tid;
      int rr = idx >> 2, seg = idx & 3;
      int sseg = seg ^ ((rr >> 1) & 3);
      load_lds16(A + (size_t)(tileM + rr) * lda + k0 + sseg * 8, &lA[idx * 8]);
      load_lds16(Wt + (size_t)(tileN + rr) * K + k0 + sseg * 8, &lB[idx * 8]);
    }
    __syncthreads();
    short8 af[4], bfr[4];
#pragma unroll
    for (int m = 0; m < 4; ++m)
      af[m] = *(const short8*)&lA[(wr * 64 + m * 16 + r0) * 32 + segr];
#pragma unroll
    for (int n = 0; n < 4; ++n)
      bfr[n] = *(const short8*)&lB[(wc * 64 + n * 16 + r0) * 32 + segr];
#pragma unroll
    for (int m = 0; m < 4; ++m)
#pragma unroll
      for (int n = 0; n < 4; ++n)
        acc[m][n] = __builtin_amdgcn_mfma_f32_16x16x32_bf16(af[m], bfr[n], acc[m][n], 0, 0, 0);
    __syncthreads();
  }
#pragma unroll
  for (int m = 0; m < 4; ++m) {
#pragma unroll
    for (int n = 0; n < 4; ++n) {
      const int col = tileN + wc * 64 + n * 16 + r0;
      const float bv = bias[col];
#pragma unroll
      for (int r = 0; r < 4; ++r) {
        const int row = tileM + wr * 64 + m * 16 + kq * 4 + r;
        float v = acc[m][n][r] + bv;
        if (act) v = v > 0.f ? v : 128.f * v;
        C[(size_t)row * ldc + col] = f2b(v);
      }
    }
  }
}

// ---------------------------------------------------------------------------
// GATv2 edge stage, rewritten:
//  A: stage xl/xr [h*12+s][260] bf16 (+zero pad rows 48..63 of xl), attS f32.
//  B: alpha dots vectorized ushort4/f32x4, pre-scaled by log2(e).
//  C: per-(dst,head) softmax in exp2-domain; A' = exp2(a-m)/den*0.25 packed
//     as bf16 into a 16x72 tile a2b (rows=dst, cols=h*12+s, zero-padded).
//  D: out[12,256] = A2[16,64pad] @ X2[64pad,256] via 2 MFMA per wave.
// ---------------------------------------------------------------------------
#define SX 260
__global__ __launch_bounds__(256) void gat_edge(
    const unsigned short* __restrict__ projS,
    const unsigned short* __restrict__ projD,
    const int* __restrict__ edges,
    const float* __restrict__ att,
    const float* __restrict__ gbias,
    float* __restrict__ outp)
{
  __shared__ __align__(16) unsigned short xl[64 * SX];
  __shared__ __align__(8)  unsigned short xr[48 * SX];
  __shared__ float attS[4 * SX];
  __shared__ float alphaS[72 * 4];
  __shared__ float AmatF[4 * 12 * 12];
  __shared__ __align__(16) unsigned short a2b[16 * 72];
  __shared__ int se_[72], de_[72];
  const int g = blockIdx.x, tid = threadIdx.x;
  const int base = g * 12;
  if (tid < 72) {
    se_[tid] = edges[g * 72 + tid] - base;
    de_[tid] = edges[ETOT + g * 72 + tid] - base;
  }
  for (int i = tid; i < 1024; i += 256)
    attS[(i >> 8) * SX + (i & 255)] = att[i];
  for (int i = tid; i < 3072; i += 256) {
    int s = i >> 8, c4 = (i & 255) * 4;
    int h = c4 >> 8, cc = c4 & 255;
    ushort4 v1 = *(const ushort4*)(projS + (size_t)(base + s) * 3072 + c4);
    ushort4 v2 = *(const ushort4*)(projD + (size_t)(base + s) * 3072 + c4);
    *(ushort4*)&xl[(h * 12 + s) * SX + cc] = v1;
    *(ushort4*)&xr[(h * 12 + s) * SX + cc] = v2;
  }
  for (int i = tid; i < 1024; i += 256)    // zero xl pad rows 48..63
    *(ushort4*)&xl[(48 + (i >> 6)) * SX + (i & 63) * 4] = (ushort4){0, 0, 0, 0};
  for (int i = tid; i < 16 * 72; i += 256) // zero A2 bf16 tile
    a2b[i] = 0;
  __syncthreads();
  // --- B: alpha[e,h] = log2e * sum_c lrelu(xl[s]+xr[d]) * att[h]
  for (int t = tid; t < 288; t += 256) {
    const int e = t >> 2, h = t & 3;
    const unsigned short* pl = &xl[(h * 12 + se_[e]) * SX];
    const unsigned short* pr = &xr[(h * 12 + de_[e]) * SX];
    const f32x4* pa = (const f32x4*)&attS[h * SX];
    float sum = 0.f;
    for (int q = 0; q < 64; ++q) {
      ushort4 a4 = *(const ushort4*)(pl + q * 4);
      ushort4 b4 = *(const ushort4*)(pr + q * 4);
      f32x4 av = pa[q];
      float v0 = b2f(a4.x) + b2f(b4.x); v0 = fmaxf(v0, 0.2f * v0);
      float v1 = b2f(a4.y) + b2f(b4.y); v1 = fmaxf(v1, 0.2f * v1);
      float v2 = b2f(a4.z) + b2f(b4.z); v2 = fmaxf(v2, 0.2f * v2);
      float v3 = b2f(a4.w) + b2f(b4.w); v3 = fmaxf(v3, 0.2f * v3);
      sum = fmaf(v0, av.x, sum); sum = fmaf(v1, av.y, sum);
      sum = fmaf(v2, av.z, sum); sum = fmaf(v3, av.w, sum);
    }
    alphaS[e * 4 + h] = sum * LOG2E;
  }
  __syncthreads();
  // --- C: softmax per (d,h), fold 1/den and 0.25 head-mean, pack bf16 A2
  if (tid < 48) {
    const int d = tid >> 2, h = tid & 3;
    float mx = -1e30f;
    for (int e = 0; e < 72; ++e)
      if (de_[e] == d) mx = fmaxf(mx, alphaS[e * 4 + h]);
#pragma unroll
    for (int s = 0; s < 12; ++s) AmatF[(h * 12 + d) * 12 + s] = 0.f;
    float dn = 0.f;
    for (int e = 0; e < 72; ++e)
      if (de_[e] == d) {
        float wv = __builtin_amdgcn_exp2f(alphaS[e * 4 + h] - mx);
        dn += wv;
        AmatF[(h * 12 + d) * 12 + se_[e]] += wv;
      }
    const float inv = 0.25f * __builtin_amdgcn_rcpf(dn + 1e-16f);
#pragma unroll
    for (int s = 0; s < 12; ++s)
      a2b[d * 72 + h * 12 + s] = f2b(AmatF[(h * 12 + d) * 12 + s] * inv);
  }
  __syncthreads();
  // --- D: out = A2 @ X2 via MFMA (each wave: 64 cols, 2 mfma per 16-col blk)
  const int w = tid >> 6, lane = tid & 63;
  const int r0 = lane & 15, kq = lane >> 4;
  const short8 afA = *(const short8*)&a2b[r0 * 72 + kq * 8];
  const short8 afB = *(const short8*)&a2b[r0 * 72 + 32 + kq * 8];
#pragma unroll
  for (int n = 0; n < 4; ++n) {
    const int col = w * 64 + n * 16 + r0;
    f32x4 oa = (f32x4){0.f, 0.f, 0.f, 0.f};
    short8 bb;
#pragma unroll
    for (int j = 0; j < 8; ++j) bb[j] = (short)xl[(kq * 8 + j) * SX + col];
    oa = __builtin_amdgcn_mfma_f32_16x16x32_bf16(afA, bb, oa, 0, 0, 0);
#pragma unroll
    for (int j = 0; j < 8; ++j) bb[j] = (short)xl[(32 + kq * 8 + j) * SX + col];
    oa = __builtin_amdgcn_mfma_f32_16x16x32_bf16(afB, bb, oa, 0, 0, 0);
    const float gb = gbias[col];
#pragma unroll
    for (int r = 0; r < 4; ++r) {
      const int d = kq * 4 + r;
      if (d < 12) outp[(size_t)(base + d) * 256 + col] = oa[r] + gb;
    }
  }
}

// ---------------------------------------------------------------------------
// CGConv edge stage, rewritten: edges sorted by dst once; per-column thread
// keeps the accumulator in a register with dst operands hoisted; hardware
// transcendentals (v_exp/v_log/v_rcp) replace libm log1pf and div sequences.
// ---------------------------------------------------------------------------
__global__ __launch_bounds__(256) void cg_edge(
    const unsigned short* __restrict__ pdF, const unsigned short* __restrict__ pdS,
    const unsigned short* __restrict__ psF, const unsigned short* __restrict__ psS,
    const unsigned short* __restrict__ hres,
    const float* __restrict__ gatp,
    const int* __restrict__ edges,
    unsigned short* __restrict__ outp)
{
  __shared__ __align__(8) unsigned short df[3072], dsb[3072];
  __shared__ __align__(8) unsigned short sfb[3072], ssb[3072];
  __shared__ unsigned char srcl[12 * 80];
  __shared__ int cnt[12];
  __shared__ int se_[72], de_[72];
  const int g = blockIdx.x, tid = threadIdx.x;
  const int base = g * 12;
  if (tid < 72) {
    se_[tid] = edges[g * 72 + tid] - base;
    de_[tid] = edges[ETOT + g * 72 + tid] - base;
  }
  for (int i = tid; i < 768; i += 256) {
    int s = i >> 6, c4 = (i & 63) * 4;
    size_t gb = (size_t)(base + s) * 3072 + c4;
    *(ushort4*)&df[s * 256 + c4]  = *(const ushort4*)(pdF + gb);
    *(ushort4*)&dsb[s * 256 + c4] = *(const ushort4*)(pdS + gb);
    *(ushort4*)&sfb[s * 256 + c4] = *(const ushort4*)(psF + gb);
    *(ushort4*)&ssb[s * 256 + c4] = *(const ushort4*)(psS + gb);
  }
  __syncthreads();
  if (tid < 12) {
    int n = 0;
    for (int e = 0; e < 72; ++e)
      if (de_[e] == tid) srcl[tid * 80 + (n++)] = (unsigned char)se_[e];
    cnt[tid] = n;
  }
  __syncthreads();
  const int c = tid;
  for (int d = 0; d < 12; ++d) {
    const float fd = b2f(df[d * 256 + c]);
    const float sd = b2f(dsb[d * 256 + c]);
    const int n = cnt[d];
    float acc = 0.f;
    for (int j = 0; j < n; ++j) {
      const int s = srcl[d * 80 + j];
      const float zf = fd + b2f(sfb[s * 256 + c]);
      const float zs = sd + b2f(ssb[s * 256 + c]);
      const float gate = __builtin_amdgcn_rcpf(1.f + __builtin_amdgcn_exp2f(-LOG2E * zf));
      const float e2 = __builtin_amdgcn_exp2f(-LOG2E * fabsf(zs));
      const float sp = fmaxf(zs, 0.f) + LN2 * __builtin_amdgcn_logf(1.f + e2);
      acc = fmaf(gate, sp, acc);
    }
    const size_t o = (size_t)(base + d) * 256 + c;
    outp[o] = f2b(b2f(hres[o]) + gatp[o] + acc);
  }
}

// ---------------------------------------------------------------------------
// logits: one wave per node, dot(f[128], W2) + b2
// ---------------------------------------------------------------------------
__global__ __launch_bounds__(256) void logits_kernel(
    const unsigned short* __restrict__ f, const float* __restrict__ W2,
    const float* __restrict__ b2, float* __restrict__ out)
{
  const int node = blockIdx.x * 4 + (threadIdx.x >> 6);
  const int lane = threadIdx.x & 63;
  const size_t o = (size_t)node * 128 + lane * 2;
  float s = b2f(f[o]) * W2[lane * 2] + b2f(f[o + 1]) * W2[lane * 2 + 1];
  for (int d = 32; d > 0; d >>= 1) s += __shfl_down(s, d, 64);
  if (lane == 0) out[node] = s + b2[0];
}

// ---------------------------------------------------------------------------
extern "C" void kernel_launch(void* const* d_in, const int* in_sizes, int n_in,
                              void* d_out, int out_size, void* d_ws, size_t ws_size,
                              hipStream_t stream) {
  const float* x_my    = (const float*)d_in[0];
  const float* x_opp   = (const float*)d_in[1];
  const int*   e_beats = (const int*)d_in[2];
  const int*   e_loses = (const int*)d_in[3];
  const int*   e_rb    = (const int*)d_in[4];
  const int*   e_rl    = (const int*)d_in[5];
  const float* enc_W   = (const float*)d_in[7];
  const float* enc_b   = (const float*)d_in[8];
  const float* gat_Wl  = (const float*)d_in[9];
  const float* gat_bl  = (const float*)d_in[10];
  const float* gat_Wr  = (const float*)d_in[11];
  const float* gat_br  = (const float*)d_in[12];
  const float* gat_att = (const float*)d_in[13];
  const float* gat_bsp = (const float*)d_in[14];
  const float* cg_Wf   = (const float*)d_in[15];
  const float* cg_bf   = (const float*)d_in[16];
  const float* cg_Ws   = (const float*)d_in[17];
  const float* cg_bs   = (const float*)d_in[18];
  const float* node_W  = (const float*)d_in[19];
  const float* node_b  = (const float*)d_in[20];
  const float* fin_W1  = (const float*)d_in[21];
  const float* fin_b1  = (const float*)d_in[22];
  const float* fin_W2  = (const float*)d_in[23];
  const float* fin_b2  = (const float*)d_in[24];

  char* wsp = (char*)d_ws;
  size_t off = 0;
  auto alloc = [&](size_t b) { char* p = wsp + off; off += (b + 255) & ~(size_t)255; return p; };
  unsigned short* wt_my   = (unsigned short*)alloc((size_t)2359296 * 2);
  unsigned short* wt_opp  = (unsigned short*)alloc((size_t)2359296 * 2);
  unsigned short* node_wt = (unsigned short*)alloc((size_t)196608 * 2);
  unsigned short* enc_wt  = (unsigned short*)alloc((size_t)8192 * 2);
  unsigned short* fin_w1t = (unsigned short*)alloc((size_t)32768 * 2);
  float*          bias_my = (float*)alloc((size_t)9216 * 4);
  float*          bias_op = (float*)alloc((size_t)9216 * 4);
  unsigned short* xb      = (unsigned short*)alloc((size_t)786432 * 2);
  unsigned short* Hb      = (unsigned short*)alloc((size_t)2 * NNODES * 256 * 2);
  unsigned short* proj_my = (unsigned short*)alloc((size_t)NNODES * 3072 * 2);
  unsigned short* proj_op = (unsigned short*)alloc((size_t)NNODES * 3072 * 2);
  float*          gat_my  = (float*)alloc((size_t)NNODES * 256 * 4);
  float*          gat_op  = (float*)alloc((size_t)NNODES * 256 * 4);
  unsigned short* node_in = (unsigned short*)alloc((size_t)2 * NNODES * 256 * 2);
  unsigned short* fbuf    = (unsigned short*)alloc((size_t)NNODES * 128 * 2);

  const int PACK_TOTAL = 2 * 2359296 + 196608 + 8192 + 32768 + 2 * 9216 + 2 * 393216;
  pack_kernel<<<(PACK_TOTAL + 255) / 256, 256, 0, stream>>>(
      gat_Wl, gat_Wr, cg_Wf, cg_Ws, node_W, enc_W, fin_W1,
      gat_bl, gat_br, cg_bf, cg_bs, x_my, x_opp,
      wt_my, wt_opp, node_wt, enc_wt, fin_w1t, bias_my, bias_op, xb);

  gemm128<<<dim3(192, 2), 256, 0, stream>>>(xb, 32, enc_wt, enc_b, Hb, 256, 32, 0);

  unsigned short* Hmy   = Hb;
  unsigned short* Hopp  = Hb + (size_t)NNODES * 256;
  unsigned short* ni_my = node_in;
  unsigned short* ni_op = node_in + (size_t)NNODES * 256;

  for (int l = 0; l < 3; ++l) {
    gemm128<<<dim3(96, 24), 256, 0, stream>>>(Hmy, 256, wt_my + (size_t)l * 786432,
                                              bias_my + l * 3072, proj_my, 3072, 256, 0);
    gemm128<<<dim3(96, 24), 256, 0, stream>>>(Hopp, 256, wt_opp + (size_t)l * 786432,
                                              bias_op + l * 3072, proj_op, 3072, 256, 0);
    gat_edge<<<NGR, 256, 0, stream>>>(proj_my, proj_op, e_beats,
                                      gat_att + (l * 2 + 0) * 1024,
                                      gat_bsp + (l * 2 + 0) * 256, gat_op);
    gat_edge<<<NGR, 256, 0, stream>>>(proj_op + 1024, proj_my + 1024, e_rl,
                                      gat_att + (l * 2 + 1) * 1024,
                                      gat_bsp + (l * 2 + 1) * 256, gat_my);
    cg_edge<<<NGR, 256, 0, stream>>>(proj_op + 2048, proj_op + 2304,
                                     proj_my + 2048, proj_my + 2304,
                                     Hopp, gat_op, e_loses, ni_op);
    cg_edge<<<NGR, 256, 0, stream>>>(proj_my + 2560, proj_my + 2816,
                                     proj_op + 2560, proj_op + 2816,
                                     Hmy, gat_my, e_rb, ni_my);
    gemm128<<<dim3(192, 2), 256, 0, stream>>>(node_in, 256, node_wt + (size_t)l * 65536,
                                              node_b + l * 256, Hb, 256, 256, 0);
  }

  gemm128<<<dim3(96, 1), 256, 0, stream>>>(Hmy, 256, fin_w1t, fin_b1, fbuf, 128, 256, 1);
  logits_kernel<<<NNODES / 4, 256, 0, stream>>>(fbuf, fin_W2, fin_b2, (float*)d_out);
}

// Round 3
// 662.694 us; speedup vs baseline: 1.7933x; 1.2589x over previous
//
#include <hip/hip_runtime.h>

#define NNODES 12288
#define ETOT   73728
#define NGR    1024
#define LOG2E  1.442695041f
#define LN2    0.6931471806f

typedef __attribute__((ext_vector_type(8))) short short8;
typedef __attribute__((ext_vector_type(4))) float f32x4;

__device__ __forceinline__ unsigned short f2b(float f) {
  unsigned x = __float_as_uint(f);
  return (unsigned short)((x + 0x7FFFu + ((x >> 16) & 1u)) >> 16);
}
__device__ __forceinline__ float b2f(unsigned short u) {
  return __uint_as_float(((unsigned)u) << 16);
}
__device__ __forceinline__ void load_lds16(const void* g, void* l) {
  __builtin_amdgcn_global_load_lds(
      (const __attribute__((address_space(1))) unsigned int*)g,
      (__attribute__((address_space(3))) unsigned int*)l, 16, 0, 0);
}
// ordered-uint encode for float atomicMax (monotone); mU init 0 == -inf
__device__ __forceinline__ unsigned fenc(float f) {
  unsigned u = __float_as_uint(f);
  return (u & 0x80000000u) ? ~u : (u | 0x80000000u);
}
__device__ __forceinline__ float fdec(unsigned e) {
  unsigned u = (e & 0x80000000u) ? (e & 0x7FFFFFFFu) : ~e;
  return __uint_as_float(u);
}

// ---------------------------------------------------------------------------
// Pack (unchanged): transpose-convert all weights to bf16 [N][K].
// ---------------------------------------------------------------------------
__global__ void pack_kernel(
    const float* __restrict__ gat_Wl, const float* __restrict__ gat_Wr,
    const float* __restrict__ cg_Wf, const float* __restrict__ cg_Ws,
    const float* __restrict__ node_W, const float* __restrict__ enc_W,
    const float* __restrict__ fin_W1,
    const float* __restrict__ gat_bl, const float* __restrict__ gat_br,
    const float* __restrict__ cg_bf, const float* __restrict__ cg_bs,
    const float* __restrict__ x_my, const float* __restrict__ x_opp,
    unsigned short* __restrict__ wt_my, unsigned short* __restrict__ wt_opp,
    unsigned short* __restrict__ node_wt, unsigned short* __restrict__ enc_wt,
    unsigned short* __restrict__ fin_w1t,
    float* __restrict__ bias_my, float* __restrict__ bias_opp,
    unsigned short* __restrict__ xb)
{
  int idx = blockIdx.x * 256 + threadIdx.x;
  if (idx < 2 * 2359296) {
    int which = idx >= 2359296;
    int t = which ? idx - 2359296 : idx;
    int l = t / 786432;
    int r = t - l * 786432;
    int n = r >> 8, k = r & 255;
    float v;
    if (!which) {
      if (n < 1024)      v = gat_Wl[((l*2+0)*256 + k)*1024 + n];
      else if (n < 2048) v = gat_Wr[((l*2+1)*256 + k)*1024 + (n-1024)];
      else if (n < 2304) v = cg_Wf[((l*2+0)*512 + 256 + k)*256 + (n-2048)];
      else if (n < 2560) v = cg_Ws[((l*2+0)*512 + 256 + k)*256 + (n-2304)];
      else if (n < 2816) v = cg_Wf[((l*2+1)*512 + k)*256 + (n-2560)];
      else               v = cg_Ws[((l*2+1)*512 + k)*256 + (n-2816)];
      wt_my[t] = f2b(v);
    } else {
      if (n < 1024)      v = gat_Wr[((l*2+0)*256 + k)*1024 + n];
      else if (n < 2048) v = gat_Wl[((l*2+1)*256 + k)*1024 + (n-1024)];
      else if (n < 2304) v = cg_Wf[((l*2+0)*512 + k)*256 + (n-2048)];
      else if (n < 2560) v = cg_Ws[((l*2+0)*512 + k)*256 + (n-2304)];
      else if (n < 2816) v = cg_Wf[((l*2+1)*512 + 256 + k)*256 + (n-2560)];
      else               v = cg_Ws[((l*2+1)*512 + 256 + k)*256 + (n-2816)];
      wt_opp[t] = f2b(v);
    }
    return;
  }
  idx -= 2 * 2359296;
  if (idx < 196608) {
    int l = idx / 65536, r = idx - l * 65536;
    int n = r >> 8, k = r & 255;
    node_wt[idx] = f2b(node_W[(l*256 + k)*256 + n]);
    return;
  }
  idx -= 196608;
  if (idx < 8192) {
    int n = idx >> 5, k = idx & 31;
    enc_wt[idx] = f2b(enc_W[k*256 + n]);
    return;
  }
  idx -= 8192;
  if (idx < 32768) {
    int n = idx >> 8, k = idx & 255;
    fin_w1t[idx] = f2b(fin_W1[k*128 + n]);
    return;
  }
  idx -= 32768;
  if (idx < 9216) {
    int l = idx / 3072, n = idx - l * 3072;
    float v;
    if (n < 1024)      v = gat_bl[(l*2+0)*1024 + n];
    else if (n < 2048) v = gat_br[(l*2+1)*1024 + (n-1024)];
    else if (n < 2560) v = 0.f;
    else if (n < 2816) v = cg_bf[(l*2+1)*256 + (n-2560)];
    else               v = cg_bs[(l*2+1)*256 + (n-2816)];
    bias_my[idx] = v;
    return;
  }
  idx -= 9216;
  if (idx < 9216) {
    int l = idx / 3072, n = idx - l * 3072;
    float v;
    if (n < 1024)      v = gat_br[(l*2+0)*1024 + n];
    else if (n < 2048) v = gat_bl[(l*2+1)*1024 + (n-1024)];
    else if (n < 2304) v = cg_bf[(l*2+0)*256 + (n-2048)];
    else if (n < 2560) v = cg_bs[(l*2+0)*256 + (n-2304)];
    else               v = 0.f;
    bias_opp[idx] = v;
    return;
  }
  idx -= 9216;
  if (idx < 2 * 393216) {
    xb[idx] = f2b(idx < 393216 ? x_my[idx] : x_opp[idx - 393216]);
  }
}

// ---------------------------------------------------------------------------
// bf16 GEMM, 128x128 tile, BK=32, 4 waves, 16x16x32 MFMA (unchanged).
// ---------------------------------------------------------------------------
__global__ __launch_bounds__(256) void gemm128(
    const unsigned short* __restrict__ A, int lda,
    const unsigned short* __restrict__ Wt,
    const float* __restrict__ bias,
    unsigned short* __restrict__ C, int ldc,
    int K, int act)
{
  __shared__ __align__(16) unsigned short lA[128 * 32];
  __shared__ __align__(16) unsigned short lB[128 * 32];
  const int tid = threadIdx.x;
  const int lane = tid & 63;
  const int w = tid >> 6;
  const int wr = w >> 1, wc = w & 1;
  const int tileM = blockIdx.x * 128;
  const int tileN = blockIdx.y * 128;
  const int r0 = lane & 15;
  const int kq = lane >> 4;
  const int segr = (kq ^ ((r0 >> 1) & 3)) * 8;

  f32x4 acc[4][4];
#pragma unroll
  for (int m = 0; m < 4; ++m)
#pragma unroll
    for (int n = 0; n < 4; ++n)
      acc[m][n] = (f32x4){0.f, 0.f, 0.f, 0.f};

  const int KT = K >> 5;
  for (int kt = 0; kt < KT; ++kt) {
    const int k0 = kt * 32;
#pragma unroll
    for (int p = 0; p < 2; ++p) {
      int idx = p * 256 + tid;
      int rr = idx >> 2, seg = idx & 3;
      int sseg = seg ^ ((rr >> 1) & 3);
      load_lds16(A + (size_t)(tileM + rr) * lda + k0 + sseg * 8, &lA[idx * 8]);
      load_lds16(Wt + (size_t)(tileN + rr) * K + k0 + sseg * 8, &lB[idx * 8]);
    }
    __syncthreads();
    short8 af[4], bfr[4];
#pragma unroll
    for (int m = 0; m < 4; ++m)
      af[m] = *(const short8*)&lA[(wr * 64 + m * 16 + r0) * 32 + segr];
#pragma unroll
    for (int n = 0; n < 4; ++n)
      bfr[n] = *(const short8*)&lB[(wc * 64 + n * 16 + r0) * 32 + segr];
#pragma unroll
    for (int m = 0; m < 4; ++m)
#pragma unroll
      for (int n = 0; n < 4; ++n)
        acc[m][n] = __builtin_amdgcn_mfma_f32_16x16x32_bf16(af[m], bfr[n], acc[m][n], 0, 0, 0);
    __syncthreads();
  }
#pragma unroll
  for (int m = 0; m < 4; ++m) {
#pragma unroll
    for (int n = 0; n < 4; ++n) {
      const int col = tileN + wc * 64 + n * 16 + r0;
      const float bv = bias[col];
#pragma unroll
      for (int r = 0; r < 4; ++r) {
        const int row = tileM + wr * 64 + m * 16 + kq * 4 + r;
        float v = acc[m][n][r] + bv;
        if (act) v = v > 0.f ? v : 128.f * v;
        C[(size_t)row * ldc + col] = f2b(v);
      }
    }
  }
}

// ---------------------------------------------------------------------------
// GATv2 edge stage v3: fully edge-parallel softmax via LDS atomics.
//  - xl (src proj, 48 rows x 256ch, pad 260) staged in LDS (used twice).
//  - xr rows read straight from global in the alpha pass (L1/L2-hot).
//  - max per (dst,head): atomicMax on ordered-uint; den & A-matrix: ds f32
//    atomicAdd (edge-parallel, no serial RMW chains).
//  - D: out[d,c] = sum_j A2[d][j]*xl[j][c] with xl column cached in VGPRs,
//    A2 rows read as broadcast f32x4. LDS 34.3KB -> 4 blocks/CU.
// ---------------------------------------------------------------------------
#define SX 260
__global__ __launch_bounds__(256) void gat_edge(
    const unsigned short* __restrict__ projS,
    const unsigned short* __restrict__ projD,
    const int* __restrict__ edges,
    const float* __restrict__ att,
    const float* __restrict__ gbias,
    float* __restrict__ outp)
{
  __shared__ __align__(16) unsigned short xl[48 * SX];
  __shared__ float attS[4 * SX];
  __shared__ float alphaS[288];
  __shared__ float wS[288];
  __shared__ unsigned mU[48];
  __shared__ float denS[48];
  __shared__ __align__(16) float A2f[12 * 48];
  __shared__ unsigned char se8[72], de8[72];
  const int g = blockIdx.x, tid = threadIdx.x;
  const int base = g * 12;

  if (tid < 72) {
    se8[tid] = (unsigned char)(edges[g * 72 + tid] - base);
    de8[tid] = (unsigned char)(edges[ETOT + g * 72 + tid] - base);
  }
  if (tid < 48) { mU[tid] = 0u; denS[tid] = 0.f; }
  for (int i = tid; i < 576; i += 256) A2f[i] = 0.f;
  for (int i = tid; i < 1024; i += 256)
    attS[(i >> 8) * SX + (i & 255)] = att[i];
  for (int i = tid; i < 3072; i += 256) {
    int s = i >> 8, c4 = (i & 255) * 4;
    int h = c4 >> 8, cc = c4 & 255;
    *(ushort4*)&xl[(h * 12 + s) * SX + cc] =
        *(const ushort4*)(projS + (size_t)(base + s) * 3072 + c4);
  }
  __syncthreads();

  // alpha + running max (edge-parallel)
  for (int t = tid; t < 288; t += 256) {
    const int e = t >> 2, h = t & 3;
    const unsigned short* pl = &xl[(h * 12 + se8[e]) * SX];
    const unsigned short* pr = projD + (size_t)(base + de8[e]) * 3072 + h * 256;
    const f32x4* pa = (const f32x4*)&attS[h * SX];
    float sum = 0.f;
    for (int q = 0; q < 64; ++q) {
      ushort4 a4 = *(const ushort4*)(pl + q * 4);
      ushort4 b4 = *(const ushort4*)(pr + q * 4);
      f32x4 av = pa[q];
      float v0 = b2f(a4.x) + b2f(b4.x); v0 = fmaxf(v0, 0.2f * v0);
      float v1 = b2f(a4.y) + b2f(b4.y); v1 = fmaxf(v1, 0.2f * v1);
      float v2 = b2f(a4.z) + b2f(b4.z); v2 = fmaxf(v2, 0.2f * v2);
      float v3 = b2f(a4.w) + b2f(b4.w); v3 = fmaxf(v3, 0.2f * v3);
      sum = fmaf(v0, av.x, sum); sum = fmaf(v1, av.y, sum);
      sum = fmaf(v2, av.z, sum); sum = fmaf(v3, av.w, sum);
    }
    sum *= LOG2E;
    alphaS[t] = sum;
    atomicMax(&mU[de8[e] * 4 + h], fenc(sum));
  }
  __syncthreads();

  // w = exp2(alpha - m); denominator (edge-parallel)
  for (int t = tid; t < 288; t += 256) {
    const int e = t >> 2, h = t & 3;
    const float m = fdec(mU[de8[e] * 4 + h]);
    const float wv = __builtin_amdgcn_exp2f(alphaS[t] - m);
    wS[t] = wv;
    atomicAdd(&denS[de8[e] * 4 + h], wv);
  }
  __syncthreads();

  // A-matrix accumulate with folded 1/den and 0.25 head-mean
  for (int t = tid; t < 288; t += 256) {
    const int e = t >> 2, h = t & 3;
    const float inv = 0.25f * __builtin_amdgcn_rcpf(denS[de8[e] * 4 + h] + 1e-16f);
    atomicAdd(&A2f[de8[e] * 48 + h * 12 + se8[e]], wS[t] * inv);
  }
  __syncthreads();

  // D: out[d,c] = sum_j A2[d][j] * xl[j][c]  (xl column cached in regs)
  {
    const int c = tid;
    float xlv[48];
#pragma unroll
    for (int j = 0; j < 48; ++j) xlv[j] = b2f(xl[j * SX + c]);
    const float gb = gbias[c];
#pragma unroll
    for (int d = 0; d < 12; ++d) {
      const f32x4* arow = (const f32x4*)&A2f[d * 48];
      float s = 0.f;
#pragma unroll
      for (int jj = 0; jj < 12; ++jj) {
        f32x4 a4 = arow[jj];
        s = fmaf(a4.x, xlv[jj * 4 + 0], s);
        s = fmaf(a4.y, xlv[jj * 4 + 1], s);
        s = fmaf(a4.z, xlv[jj * 4 + 2], s);
        s = fmaf(a4.w, xlv[jj * 4 + 3], s);
      }
      outp[(size_t)(base + d) * 256 + c] = s + gb;
    }
  }
}

// ---------------------------------------------------------------------------
// CGConv edge stage (unchanged from R1).
// ---------------------------------------------------------------------------
__global__ __launch_bounds__(256) void cg_edge(
    const unsigned short* __restrict__ pdF, const unsigned short* __restrict__ pdS,
    const unsigned short* __restrict__ psF, const unsigned short* __restrict__ psS,
    const unsigned short* __restrict__ hres,
    const float* __restrict__ gatp,
    const int* __restrict__ edges,
    unsigned short* __restrict__ outp)
{
  __shared__ __align__(8) unsigned short df[3072], dsb[3072];
  __shared__ __align__(8) unsigned short sfb[3072], ssb[3072];
  __shared__ unsigned char srcl[12 * 80];
  __shared__ int cnt[12];
  __shared__ int se_[72], de_[72];
  const int g = blockIdx.x, tid = threadIdx.x;
  const int base = g * 12;
  if (tid < 72) {
    se_[tid] = edges[g * 72 + tid] - base;
    de_[tid] = edges[ETOT + g * 72 + tid] - base;
  }
  for (int i = tid; i < 768; i += 256) {
    int s = i >> 6, c4 = (i & 63) * 4;
    size_t gb = (size_t)(base + s) * 3072 + c4;
    *(ushort4*)&df[s * 256 + c4]  = *(const ushort4*)(pdF + gb);
    *(ushort4*)&dsb[s * 256 + c4] = *(const ushort4*)(pdS + gb);
    *(ushort4*)&sfb[s * 256 + c4] = *(const ushort4*)(psF + gb);
    *(ushort4*)&ssb[s * 256 + c4] = *(const ushort4*)(psS + gb);
  }
  __syncthreads();
  if (tid < 12) {
    int n = 0;
    for (int e = 0; e < 72; ++e)
      if (de_[e] == tid) srcl[tid * 80 + (n++)] = (unsigned char)se_[e];
    cnt[tid] = n;
  }
  __syncthreads();
  const int c = tid;
  for (int d = 0; d < 12; ++d) {
    const float fd = b2f(df[d * 256 + c]);
    const float sd = b2f(dsb[d * 256 + c]);
    const int n = cnt[d];
    float acc = 0.f;
    for (int j = 0; j < n; ++j) {
      const int s = srcl[d * 80 + j];
      const float zf = fd + b2f(sfb[s * 256 + c]);
      const float zs = sd + b2f(ssb[s * 256 + c]);
      const float gate = __builtin_amdgcn_rcpf(1.f + __builtin_amdgcn_exp2f(-LOG2E * zf));
      const float e2 = __builtin_amdgcn_exp2f(-LOG2E * fabsf(zs));
      const float sp = fmaxf(zs, 0.f) + LN2 * __builtin_amdgcn_logf(1.f + e2);
      acc = fmaf(gate, sp, acc);
    }
    const size_t o = (size_t)(base + d) * 256 + c;
    outp[o] = f2b(b2f(hres[o]) + gatp[o] + acc);
  }
}

// ---------------------------------------------------------------------------
// logits: one wave per node, dot(f[128], W2) + b2
// ---------------------------------------------------------------------------
__global__ __launch_bounds__(256) void logits_kernel(
    const unsigned short* __restrict__ f, const float* __restrict__ W2,
    const float* __restrict__ b2, float* __restrict__ out)
{
  const int node = blockIdx.x * 4 + (threadIdx.x >> 6);
  const int lane = threadIdx.x & 63;
  const size_t o = (size_t)node * 128 + lane * 2;
  float s = b2f(f[o]) * W2[lane * 2] + b2f(f[o + 1]) * W2[lane * 2 + 1];
  for (int d = 32; d > 0; d >>= 1) s += __shfl_down(s, d, 64);
  if (lane == 0) out[node] = s + b2[0];
}

// ---------------------------------------------------------------------------
extern "C" void kernel_launch(void* const* d_in, const int* in_sizes, int n_in,
                              void* d_out, int out_size, void* d_ws, size_t ws_size,
                              hipStream_t stream) {
  const float* x_my    = (const float*)d_in[0];
  const float* x_opp   = (const float*)d_in[1];
  const int*   e_beats = (const int*)d_in[2];
  const int*   e_loses = (const int*)d_in[3];
  const int*   e_rb    = (const int*)d_in[4];
  const int*   e_rl    = (const int*)d_in[5];
  const float* enc_W   = (const float*)d_in[7];
  const float* enc_b   = (const float*)d_in[8];
  const float* gat_Wl  = (const float*)d_in[9];
  const float* gat_bl  = (const float*)d_in[10];
  const float* gat_Wr  = (const float*)d_in[11];
  const float* gat_br  = (const float*)d_in[12];
  const float* gat_att = (const float*)d_in[13];
  const float* gat_bsp = (const float*)d_in[14];
  const float* cg_Wf   = (const float*)d_in[15];
  const float* cg_bf   = (const float*)d_in[16];
  const float* cg_Ws   = (const float*)d_in[17];
  const float* cg_bs   = (const float*)d_in[18];
  const float* node_W  = (const float*)d_in[19];
  const float* node_b  = (const float*)d_in[20];
  const float* fin_W1  = (const float*)d_in[21];
  const float* fin_b1  = (const float*)d_in[22];
  const float* fin_W2  = (const float*)d_in[23];
  const float* fin_b2  = (const float*)d_in[24];

  char* wsp = (char*)d_ws;
  size_t off = 0;
  auto alloc = [&](size_t b) { char* p = wsp + off; off += (b + 255) & ~(size_t)255; return p; };
  unsigned short* wt_my   = (unsigned short*)alloc((size_t)2359296 * 2);
  unsigned short* wt_opp  = (unsigned short*)alloc((size_t)2359296 * 2);
  unsigned short* node_wt = (unsigned short*)alloc((size_t)196608 * 2);
  unsigned short* enc_wt  = (unsigned short*)alloc((size_t)8192 * 2);
  unsigned short* fin_w1t = (unsigned short*)alloc((size_t)32768 * 2);
  float*          bias_my = (float*)alloc((size_t)9216 * 4);
  float*          bias_op = (float*)alloc((size_t)9216 * 4);
  unsigned short* xb      = (unsigned short*)alloc((size_t)786432 * 2);
  unsigned short* Hb      = (unsigned short*)alloc((size_t)2 * NNODES * 256 * 2);
  unsigned short* proj_my = (unsigned short*)alloc((size_t)NNODES * 3072 * 2);
  unsigned short* proj_op = (unsigned short*)alloc((size_t)NNODES * 3072 * 2);
  float*          gat_my  = (float*)alloc((size_t)NNODES * 256 * 4);
  float*          gat_op  = (float*)alloc((size_t)NNODES * 256 * 4);
  unsigned short* node_in = (unsigned short*)alloc((size_t)2 * NNODES * 256 * 2);
  unsigned short* fbuf    = (unsigned short*)alloc((size_t)NNODES * 128 * 2);

  const int PACK_TOTAL = 2 * 2359296 + 196608 + 8192 + 32768 + 2 * 9216 + 2 * 393216;
  pack_kernel<<<(PACK_TOTAL + 255) / 256, 256, 0, stream>>>(
      gat_Wl, gat_Wr, cg_Wf, cg_Ws, node_W, enc_W, fin_W1,
      gat_bl, gat_br, cg_bf, cg_bs, x_my, x_opp,
      wt_my, wt_opp, node_wt, enc_wt, fin_w1t, bias_my, bias_op, xb);

  gemm128<<<dim3(192, 2), 256, 0, stream>>>(xb, 32, enc_wt, enc_b, Hb, 256, 32, 0);

  unsigned short* Hmy   = Hb;
  unsigned short* Hopp  = Hb + (size_t)NNODES * 256;
  unsigned short* ni_my = node_in;
  unsigned short* ni_op = node_in + (size_t)NNODES * 256;

  for (int l = 0; l < 3; ++l) {
    gemm128<<<dim3(96, 24), 256, 0, stream>>>(Hmy, 256, wt_my + (size_t)l * 786432,
                                              bias_my + l * 3072, proj_my, 3072, 256, 0);
    gemm128<<<dim3(96, 24), 256, 0, stream>>>(Hopp, 256, wt_opp + (size_t)l * 786432,
                                              bias_op + l * 3072, proj_op, 3072, 256, 0);
    gat_edge<<<NGR, 256, 0, stream>>>(proj_my, proj_op, e_beats,
                                      gat_att + (l * 2 + 0) * 1024,
                                      gat_bsp + (l * 2 + 0) * 256, gat_op);
    gat_edge<<<NGR, 256, 0, stream>>>(proj_op + 1024, proj_my + 1024, e_rl,
                                      gat_att + (l * 2 + 1) * 1024,
                                      gat_bsp + (l * 2 + 1) * 256, gat_my);
    cg_edge<<<NGR, 256, 0, stream>>>(proj_op + 2048, proj_op + 2304,
                                     proj_my + 2048, proj_my + 2304,
                                     Hopp, gat_op, e_loses, ni_op);
    cg_edge<<<NGR, 256, 0, stream>>>(proj_my + 2560, proj_my + 2816,
                                     proj_op + 2560, proj_op + 2816,
                                     Hmy, gat_my, e_rb, ni_my);
    gemm128<<<dim3(192, 2), 256, 0, stream>>>(node_in, 256, node_wt + (size_t)l * 65536,
                                              node_b + l * 256, Hb, 256, 256, 0);
  }

  gemm128<<<dim3(96, 1), 256, 0, stream>>>(Hmy, 256, fin_w1t, fin_b1, fbuf, 128, 256, 1);
  logits_kernel<<<NNODES / 4, 256, 0, stream>>>(fbuf, fin_W2, fin_b2, (float*)d_out);
}